// Round 5
// baseline (794.703 us; speedup 1.0000x reference)
//
#include <hip/hip_runtime.h>
#include <stdint.h>

#define N_NODES 50000
#define N_EDGES 800000
#define FEAT    128
#define NGRAPH  64
#define SLICE   32                      // features per aggregation pass
#define NPASS   (FEAT / SLICE)          // 4
#define SLICE_ELEMS ((size_t)N_NODES * SLICE)

typedef __attribute__((ext_vector_type(8))) short short8;
typedef __attribute__((ext_vector_type(4))) float floatx4;

static __device__ __forceinline__ float bf2f(ushort u) {
  return __uint_as_float(((uint32_t)u) << 16);
}
static __device__ __forceinline__ ushort f2bf(float f) {
  uint32_t x = __float_as_uint(f);
  x += 0x7FFF + ((x >> 16) & 1);   // RNE
  return (ushort)(x >> 16);
}

// ---------------- fp32 row-major -> bf16 slice layout (x) ----------------
// out[(c>>5)*N*32 + node*32 + (c&31)]
__global__ __launch_bounds__(256) void cvt_slice(const float* __restrict__ in,
                                                 ushort* __restrict__ out) {
  int idx = blockIdx.x * 256 + threadIdx.x;   // one float4 per thread
  if (idx >= N_NODES * (FEAT / 4)) return;
  int node = idx >> 5;          // 32 float4 per node row
  int q = idx & 31;             // cols 4q..4q+3 (within one 32-slice: 4|32)
  float4 v = ((const float4*)in)[idx];
  ushort4 u;
  u.x = f2bf(v.x); u.y = f2bf(v.y); u.z = f2bf(v.z); u.w = f2bf(v.w);
  int c0 = q * 4;
  int sl = c0 >> 5, off = c0 & 31;
  *(ushort4*)(out + sl * SLICE_ELEMS + (size_t)node * SLICE + off) = u;
}

// ---------------- fp32 -> bf16 row-major (conv weights) ------------------
__global__ __launch_bounds__(256) void cvt_bf16(const float* __restrict__ in,
                                                ushort* __restrict__ out, int n4) {
  int i = blockIdx.x * 256 + threadIdx.x;
  if (i >= n4) return;
  float4 v = ((const float4*)in)[i];
  ushort4 u;
  u.x = f2bf(v.x); u.y = f2bf(v.y); u.z = f2bf(v.z); u.w = f2bf(v.w);
  ((ushort4*)out)[i] = u;
}

// ---------------- degree count -------------------------------------------
__global__ __launch_bounds__(256) void count_deg(const int* __restrict__ dst,
                                                 int* __restrict__ cnt) {
  int e = blockIdx.x * 256 + threadIdx.x;
  if (e < N_EDGES) atomicAdd(&cnt[dst[e]], 1);
}

__global__ __launch_bounds__(256) void compute_dinv(const int* __restrict__ cnt,
                                                    float* __restrict__ dinv) {
  int i = blockIdx.x * 256 + threadIdx.x;
  if (i < N_NODES) dinv[i] = rsqrtf((float)cnt[i] + 1.0f);
}

// ---------------- exclusive scan (3 kernels) -----------------------------
__global__ __launch_bounds__(256) void scan1(const int* __restrict__ cnt,
                                             int* __restrict__ ptr,
                                             int* __restrict__ bsums) {
  __shared__ int tmp[256];
  int i = blockIdx.x * 256 + threadIdx.x;
  int v = (i < N_NODES) ? cnt[i] : 0;
  tmp[threadIdx.x] = v;
  __syncthreads();
  for (int off = 1; off < 256; off <<= 1) {
    int t = (threadIdx.x >= off) ? tmp[threadIdx.x - off] : 0;
    __syncthreads();
    tmp[threadIdx.x] += t;
    __syncthreads();
  }
  if (i < N_NODES) ptr[i] = tmp[threadIdx.x] - v;           // exclusive
  if (threadIdx.x == 255) bsums[blockIdx.x] = tmp[255];
}

__global__ __launch_bounds__(256) void scan2(int* __restrict__ bsums, int nb) {
  __shared__ int tmp[256];
  int v = (threadIdx.x < nb) ? bsums[threadIdx.x] : 0;
  tmp[threadIdx.x] = v;
  __syncthreads();
  for (int off = 1; off < 256; off <<= 1) {
    int t = (threadIdx.x >= off) ? tmp[threadIdx.x - off] : 0;
    __syncthreads();
    tmp[threadIdx.x] += t;
    __syncthreads();
  }
  if (threadIdx.x < nb) bsums[threadIdx.x] = tmp[threadIdx.x] - v;  // exclusive
}

__global__ __launch_bounds__(256) void scan3(int* __restrict__ ptr,
                                             int* __restrict__ cursor,
                                             const int* __restrict__ bsums) {
  int i = blockIdx.x * 256 + threadIdx.x;
  if (i < N_NODES) {
    int p = ptr[i] + bsums[blockIdx.x];
    ptr[i] = p;
    cursor[i] = p;
  }
}

// ---------------- CSR fill (src + fused norm) ----------------------------
__global__ __launch_bounds__(256) void fill_csr(const int* __restrict__ src,
                                                const int* __restrict__ dst,
                                                const float* __restrict__ dinv,
                                                int* __restrict__ cursor,
                                                int2* __restrict__ edges) {
  int e = blockIdx.x * 256 + threadIdx.x;
  if (e >= N_EDGES) return;
  int s = src[e], d = dst[e];
  int pos = atomicAdd(&cursor[d], 1);
  float nrm = dinv[s] * dinv[d];
  edges[pos] = make_int2(s, __float_as_int(nrm));
}

// ---------------- GEMM [N,128] x [128,128], slice in / slice out ---------
// X: bf16 slices [4][N][32]; W: bf16 row-major [128][128]; OUT: bf16 slices.
__global__ __launch_bounds__(256) void gemm128(const ushort* __restrict__ X,
                                               const ushort* __restrict__ W,
                                               ushort* __restrict__ OUT) {
  int wave = (blockIdx.x * 256 + threadIdx.x) >> 6;
  int lane = threadIdx.x & 63;
  int mt = wave >> 3;  // 8 n-tiles per m-tile
  int nt = wave & 7;
  if (mt >= N_NODES / 16) return;
  int m0 = mt * 16, n0 = nt * 16;
  int r = lane & 15, quad = lane >> 4;
  floatx4 acc = {0.f, 0.f, 0.f, 0.f};
#pragma unroll
  for (int kb = 0; kb < 4; ++kb) {
    // k-block kb == slice kb; within slice, offset quad*8 (contiguous 16B)
    short8 a = *(const short8*)(X + kb * SLICE_ELEMS +
                                (size_t)(m0 + r) * SLICE + quad * 8);
    int k0 = kb * 32 + quad * 8;
    short8 b;
#pragma unroll
    for (int j = 0; j < 8; ++j) b[j] = (short)W[(size_t)(k0 + j) * FEAT + n0 + r];
    acc = __builtin_amdgcn_mfma_f32_16x16x32_bf16(a, b, acc, 0, 0, 0);
  }
  int c = n0 + r;                       // global col; [n0,n0+16) never crosses 32
  int sl = c >> 5, off = c & 31;
  ushort* ocol = OUT + sl * SLICE_ELEMS + off;
#pragma unroll
  for (int reg = 0; reg < 4; ++reg) {
    int row = quad * 4 + reg;
    ocol[(size_t)(m0 + row) * SLICE] = f2bf(acc[reg]);
  }
}

// ---------------- aggregation, one 32-feature slice pass -----------------
// wave = node; lanes 0-31 -> even edges, 32-63 -> odd edges; feat = lane&31.
// mode 0: h = relu(agg + b) -> bf16 slice Hout
// mode 1: atomicAdd(agg + b) into f_sum[batch[v]*128 + c]
__global__ __launch_bounds__(256) void agg_slice(const ushort* __restrict__ msg,
                                                 const float* __restrict__ dinv,
                                                 const int* __restrict__ ptr,
                                                 const int* __restrict__ cnt,
                                                 const int2* __restrict__ edges,
                                                 const float* __restrict__ bias,
                                                 ushort* __restrict__ Hout,
                                                 float* __restrict__ f_sum,
                                                 const int* __restrict__ batch,
                                                 int mode, int p) {
  int wave = (blockIdx.x * 256 + threadIdx.x) >> 6;
  if (wave >= N_NODES) return;
  int lane = threadIdx.x & 63;
  int e2 = lane >> 5, feat = lane & 31;
  const ushort* ms = msg + p * SLICE_ELEMS;
  int v = wave;
  float di = dinv[v];
  float acc = 0.f;
  if (e2 == 0) acc = bf2f(ms[(size_t)v * SLICE + feat]) * di * di;  // self loop
  int start = ptr[v];
  int n = cnt[v];
  int fp = n >> 1;            // full pairs (both half-waves valid)
  int j = 0;
  for (; j + 2 <= fp; j += 2) {
    int2 ea = edges[start + 2 * j + e2];
    int2 eb = edges[start + 2 * j + 2 + e2];
    float ga = bf2f(ms[(size_t)ea.x * SLICE + feat]);
    float gb = bf2f(ms[(size_t)eb.x * SLICE + feat]);
    acc = fmaf(__int_as_float(ea.y), ga, acc);
    acc = fmaf(__int_as_float(eb.y), gb, acc);
  }
  for (; j < fp; ++j) {
    int2 ea = edges[start + 2 * j + e2];
    acc = fmaf(__int_as_float(ea.y), bf2f(ms[(size_t)ea.x * SLICE + feat]), acc);
  }
  if ((n & 1) && e2 == 0) {   // odd tail edge on lower half-wave
    int2 ea = edges[start + n - 1];
    acc = fmaf(__int_as_float(ea.y), bf2f(ms[(size_t)ea.x * SLICE + feat]), acc);
  }
  acc += __shfl_down(acc, 32, 64);
  if (e2 == 0) {
    int c = p * SLICE + feat;
    float val = acc + bias[c];
    if (mode == 0) {
      val = fmaxf(val, 0.f);
      Hout[p * SLICE_ELEMS + (size_t)v * SLICE + feat] = f2bf(val);
    } else {
      atomicAdd(&f_sum[batch[v] * FEAT + c], val);
    }
  }
}

// ---------------- per-graph node counts (LDS binned) ---------------------
__global__ __launch_bounds__(256) void count_graphs(const int* __restrict__ batch,
                                                    float* __restrict__ cnt_g) {
  __shared__ int bins[NGRAPH];
  if (threadIdx.x < NGRAPH) bins[threadIdx.x] = 0;
  __syncthreads();
  int i = blockIdx.x * 256 + threadIdx.x;
  if (i < N_NODES) atomicAdd(&bins[batch[i]], 1);
  __syncthreads();
  if (threadIdx.x < NGRAPH && bins[threadIdx.x] > 0)
    atomicAdd(&cnt_g[threadIdx.x], (float)bins[threadIdx.x]);
}

// ---------------- finalize f = sums / cnt (fp32, output 0) ---------------
__global__ __launch_bounds__(256) void finalize_f(const float* __restrict__ f_sum,
                                                  const float* __restrict__ cnt_g,
                                                  float* __restrict__ out_f) {
  int i = blockIdx.x * 256 + threadIdx.x;
  if (i < NGRAPH * FEAT) {
    float c = fmaxf(cnt_g[i >> 7], 1.0f);
    out_f[i] = f_sum[i] / c;
  }
}

// ---------------- FC head: split-K atomic GEMM ---------------------------
__global__ __launch_bounds__(256) void fc_init(const float* __restrict__ b,
                                               float* __restrict__ out, int C) {
  int i = blockIdx.x * 256 + threadIdx.x;
  if (i < NGRAPH * C) out[i] = b[i % C];
}

__global__ __launch_bounds__(256) void fc_accum(const float* __restrict__ in,
                                                const float* __restrict__ w,
                                                float* __restrict__ out,
                                                int K, int C, int relu_in,
                                                int cstrips, int kchunks) {
  int wave = (blockIdx.x * 256 + threadIdx.x) >> 6;
  int lane = threadIdx.x & 63;
  int perrow = cstrips * kchunks;
  int r = wave / perrow;
  if (r >= NGRAPH) return;
  int rem = wave - r * perrow;
  int cs = rem / kchunks;
  int kc = rem - cs * kchunks;
  int c = cs * 64 + lane;
  if (c >= C) return;
  const float* inr = in + (size_t)r * K + kc * 64;
  const float* wp = w + (size_t)(kc * 64) * C + c;
  float a0 = 0.f, a1 = 0.f, a2 = 0.f, a3 = 0.f;
#pragma unroll 4
  for (int k = 0; k < 64; k += 4) {
    float i0 = inr[k], i1 = inr[k + 1], i2 = inr[k + 2], i3 = inr[k + 3];
    if (relu_in) {
      i0 = fmaxf(i0, 0.f); i1 = fmaxf(i1, 0.f);
      i2 = fmaxf(i2, 0.f); i3 = fmaxf(i3, 0.f);
    }
    a0 = fmaf(i0, wp[(size_t)k * C], a0);
    a1 = fmaf(i1, wp[(size_t)(k + 1) * C], a1);
    a2 = fmaf(i2, wp[(size_t)(k + 2) * C], a2);
    a3 = fmaf(i3, wp[(size_t)(k + 3) * C], a3);
  }
  atomicAdd(&out[(size_t)r * C + c], (a0 + a1) + (a2 + a3));
}

static inline void fc_run(const float* in, const float* w, const float* b,
                          float* out, int K, int C, int relu_in,
                          hipStream_t stream) {
  int cstrips = (C + 63) / 64;
  int kchunks = K / 64;
  fc_init<<<(NGRAPH * C + 255) / 256, 256, 0, stream>>>(b, out, C);
  int waves = NGRAPH * cstrips * kchunks;
  fc_accum<<<(waves * 64 + 255) / 256, 256, 0, stream>>>(in, w, out, K, C,
                                                         relu_in, cstrips, kchunks);
}

// =========================================================================
extern "C" void kernel_launch(void* const* d_in, const int* in_sizes, int n_in,
                              void* d_out, int out_size, void* d_ws, size_t ws_size,
                              hipStream_t stream) {
  const float* x         = (const float*)d_in[0];
  const int*   ei        = (const int*)d_in[1];     // [2][E]: row0 src, row1 dst
  const int*   batch     = (const int*)d_in[2];
  const float* conv_w[3] = {(const float*)d_in[3], (const float*)d_in[5], (const float*)d_in[7]};
  const float* conv_b[3] = {(const float*)d_in[4], (const float*)d_in[6], (const float*)d_in[8]};
  const float* fc_w[5]   = {(const float*)d_in[9],  (const float*)d_in[11],
                            (const float*)d_in[13], (const float*)d_in[15],
                            (const float*)d_in[17]};
  const float* fc_b[5]   = {(const float*)d_in[10], (const float*)d_in[12],
                            (const float*)d_in[14], (const float*)d_in[16],
                            (const float*)d_in[18]};
  const int* e_src = ei;
  const int* e_dst = ei + N_EDGES;
  float* out_f = (float*)d_out;                  // [64][128] fp32  (output 0)
  float* out_y = (float*)d_out + NGRAPH * FEAT;  // [64][10]  fp32  (output 1)

  char* p = (char*)d_ws;
  auto carve = [&](size_t bytes) {
    char* r = p;
    p += (bytes + 255) & ~(size_t)255;
    return r;
  };
  int*    cnt_i   = (int*)carve(N_NODES * 4);
  float*  dinv    = (float*)carve(N_NODES * 4);
  int*    csr_ptr = (int*)carve(N_NODES * 4);
  int*    cursor  = (int*)carve(N_NODES * 4);
  int*    bsums   = (int*)carve(256 * 4);
  int2*   edges   = (int2*)carve((size_t)N_EDGES * 8);
  ushort* xsl     = (ushort*)carve(SLICE_ELEMS * NPASS * 2);   // x, slice layout
  ushort* wb      = (ushort*)carve((size_t)3 * FEAT * FEAT * 2);
  ushort* msl     = (ushort*)carve(SLICE_ELEMS * NPASS * 2);   // messages (XW)
  ushort* hsl     = (ushort*)carve(SLICE_ELEMS * NPASS * 2);   // h between convs
  float*  f_sum   = (float*)carve(NGRAPH * FEAT * 4);
  float*  cnt_g   = (float*)carve(NGRAPH * 4);
  float*  act1    = (float*)carve(NGRAPH * 1024 * 4);
  float*  act2    = (float*)carve(NGRAPH * 512 * 4);
  float*  act3    = (float*)carve(NGRAPH * 256 * 4);
  float*  act4    = (float*)carve(NGRAPH * 128 * 4);

  const int BLK_E = (N_EDGES + 255) / 256;
  const int BLK_N = (N_NODES + 255) / 256;

  hipMemsetAsync(cnt_i, 0, N_NODES * 4, stream);
  hipMemsetAsync(f_sum, 0, NGRAPH * FEAT * 4, stream);
  hipMemsetAsync(cnt_g, 0, NGRAPH * 4, stream);

  // ---- prep: x -> bf16 slices, conv weights -> bf16 ----
  cvt_slice<<<(N_NODES * 32 + 255) / 256, 256, 0, stream>>>(x, xsl);
  cvt_bf16<<<(FEAT * FEAT / 4 + 255) / 256, 256, 0, stream>>>(conv_w[0], wb,                   FEAT * FEAT / 4);
  cvt_bf16<<<(FEAT * FEAT / 4 + 255) / 256, 256, 0, stream>>>(conv_w[1], wb + FEAT * FEAT,     FEAT * FEAT / 4);
  cvt_bf16<<<(FEAT * FEAT / 4 + 255) / 256, 256, 0, stream>>>(conv_w[2], wb + 2 * FEAT * FEAT, FEAT * FEAT / 4);

  // ---- build CSR + norms (reused by all 3 convs) ----
  count_deg<<<BLK_E, 256, 0, stream>>>(e_dst, cnt_i);
  compute_dinv<<<BLK_N, 256, 0, stream>>>(cnt_i, dinv);
  scan1<<<BLK_N, 256, 0, stream>>>(cnt_i, csr_ptr, bsums);
  scan2<<<1, 256, 0, stream>>>(bsums, BLK_N);
  scan3<<<BLK_N, 256, 0, stream>>>(csr_ptr, cursor, bsums);
  fill_csr<<<BLK_E, 256, 0, stream>>>(e_src, e_dst, dinv, cursor, edges);

  const int GEMM_BLKS = (N_NODES / 16) * 8 / 4;
  const int AGG_BLKS  = (N_NODES + 3) / 4;   // 1 wave/node, 4 waves/block

  for (int conv = 0; conv < 3; ++conv) {
    const ushort* in_sl = (conv == 0) ? xsl : hsl;
    int mode = (conv == 2) ? 1 : 0;
    gemm128<<<GEMM_BLKS, 256, 0, stream>>>(in_sl, wb + conv * FEAT * FEAT, msl);
    for (int pass = 0; pass < NPASS; ++pass) {
      agg_slice<<<AGG_BLKS, 256, 0, stream>>>(msl, dinv, csr_ptr, cnt_i, edges,
                                              conv_b[conv], hsl, f_sum, batch,
                                              mode, pass);
    }
  }

  // ---- pool ----
  count_graphs<<<BLK_N, 256, 0, stream>>>(batch, cnt_g);
  finalize_f<<<(NGRAPH * FEAT + 255) / 256, 256, 0, stream>>>(f_sum, cnt_g, out_f);

  // ---- FC head: split-K atomic GEMMs, relu fused into next layer's read ----
  fc_run(out_f, fc_w[0], fc_b[0], act1, 128, 1024, 0, stream);
  fc_run(act1,  fc_w[1], fc_b[1], act2, 1024, 512, 1, stream);
  fc_run(act2,  fc_w[2], fc_b[2], act3, 512, 256, 1, stream);
  fc_run(act3,  fc_w[3], fc_b[3], act4, 256, 128, 1, stream);
  fc_run(act4,  fc_w[4], fc_b[4], out_y, 128, 10, 1, stream);
}

// Round 6
// 529.442 us; speedup vs baseline: 1.5010x; 1.5010x over previous
//
#include <hip/hip_runtime.h>
#include <stdint.h>

#define N_NODES 50000
#define N_EDGES 800000
#define FEAT    128
#define NGRAPH  64

typedef __attribute__((ext_vector_type(8))) short short8;
typedef __attribute__((ext_vector_type(4))) float floatx4;

static __device__ __forceinline__ ushort f2bf(float f) {
  uint32_t x = __float_as_uint(f);
  x += 0x7FFF + ((x >> 16) & 1);   // RNE
  return (ushort)(x >> 16);
}
// unpack packed bf16 pair (as uint) -> two floats
static __device__ __forceinline__ float bfLo(uint32_t u) {
  return __uint_as_float(u << 16);
}
static __device__ __forceinline__ float bfHi(uint32_t u) {
  return __uint_as_float(u & 0xFFFF0000u);
}

// ---------------- fp32 -> bf16 row-major ---------------------------------
__global__ __launch_bounds__(256) void cvt_bf16(const float* __restrict__ in,
                                                ushort* __restrict__ out, int n4) {
  int i = blockIdx.x * 256 + threadIdx.x;
  if (i >= n4) return;
  float4 v = ((const float4*)in)[i];
  ushort4 u;
  u.x = f2bf(v.x); u.y = f2bf(v.y); u.z = f2bf(v.z); u.w = f2bf(v.w);
  ((ushort4*)out)[i] = u;
}

// ---------------- degree count -------------------------------------------
__global__ __launch_bounds__(256) void count_deg(const int* __restrict__ dst,
                                                 int* __restrict__ cnt) {
  int e = blockIdx.x * 256 + threadIdx.x;
  if (e < N_EDGES) atomicAdd(&cnt[dst[e]], 1);
}

__global__ __launch_bounds__(256) void compute_dinv(const int* __restrict__ cnt,
                                                    float* __restrict__ dinv) {
  int i = blockIdx.x * 256 + threadIdx.x;
  if (i < N_NODES) dinv[i] = rsqrtf((float)cnt[i] + 1.0f);
}

// ---------------- exclusive scan (3 kernels) -----------------------------
__global__ __launch_bounds__(256) void scan1(const int* __restrict__ cnt,
                                             int* __restrict__ ptr,
                                             int* __restrict__ bsums) {
  __shared__ int tmp[256];
  int i = blockIdx.x * 256 + threadIdx.x;
  int v = (i < N_NODES) ? cnt[i] : 0;
  tmp[threadIdx.x] = v;
  __syncthreads();
  for (int off = 1; off < 256; off <<= 1) {
    int t = (threadIdx.x >= off) ? tmp[threadIdx.x - off] : 0;
    __syncthreads();
    tmp[threadIdx.x] += t;
    __syncthreads();
  }
  if (i < N_NODES) ptr[i] = tmp[threadIdx.x] - v;           // exclusive
  if (threadIdx.x == 255) bsums[blockIdx.x] = tmp[255];
}

__global__ __launch_bounds__(256) void scan2(int* __restrict__ bsums, int nb) {
  __shared__ int tmp[256];
  int v = (threadIdx.x < nb) ? bsums[threadIdx.x] : 0;
  tmp[threadIdx.x] = v;
  __syncthreads();
  for (int off = 1; off < 256; off <<= 1) {
    int t = (threadIdx.x >= off) ? tmp[threadIdx.x - off] : 0;
    __syncthreads();
    tmp[threadIdx.x] += t;
    __syncthreads();
  }
  if (threadIdx.x < nb) bsums[threadIdx.x] = tmp[threadIdx.x] - v;  // exclusive
}

__global__ __launch_bounds__(256) void scan3(int* __restrict__ ptr,
                                             int* __restrict__ cursor,
                                             const int* __restrict__ bsums) {
  int i = blockIdx.x * 256 + threadIdx.x;
  if (i < N_NODES) {
    int p = ptr[i] + bsums[blockIdx.x];
    ptr[i] = p;
    cursor[i] = p;
  }
}

// ---------------- CSR fill (src + fused norm) ----------------------------
__global__ __launch_bounds__(256) void fill_csr(const int* __restrict__ src,
                                                const int* __restrict__ dst,
                                                const float* __restrict__ dinv,
                                                int* __restrict__ cursor,
                                                int2* __restrict__ edges) {
  int e = blockIdx.x * 256 + threadIdx.x;
  if (e >= N_EDGES) return;
  int s = src[e], d = dst[e];
  int pos = atomicAdd(&cursor[d], 1);
  float nrm = dinv[s] * dinv[d];
  edges[pos] = make_int2(s, __float_as_int(nrm));
}

// ---------------- GEMM [M,128] x [128,128] via MFMA bf16, bf16 out -------
__global__ __launch_bounds__(256) void gemm128(const ushort* __restrict__ X,
                                               const ushort* __restrict__ W,
                                               ushort* __restrict__ XW,
                                               int nTilesM) {
  int wave = (blockIdx.x * 256 + threadIdx.x) >> 6;
  int lane = threadIdx.x & 63;
  int mt = wave >> 3;  // 8 n-tiles per m-tile
  int nt = wave & 7;
  if (mt >= nTilesM) return;
  int m0 = mt * 16, n0 = nt * 16;
  int r = lane & 15, quad = lane >> 4;
  floatx4 acc = {0.f, 0.f, 0.f, 0.f};
  const ushort* xrow = X + (size_t)(m0 + r) * FEAT;
#pragma unroll
  for (int kb = 0; kb < 4; ++kb) {
    int k0 = kb * 32 + quad * 8;
    short8 a = *(const short8*)(xrow + k0);
    short8 b;
#pragma unroll
    for (int j = 0; j < 8; ++j) b[j] = (short)W[(size_t)(k0 + j) * FEAT + n0 + r];
    acc = __builtin_amdgcn_mfma_f32_16x16x32_bf16(a, b, acc, 0, 0, 0);
  }
#pragma unroll
  for (int reg = 0; reg < 4; ++reg) {
    int row = quad * 4 + reg;
    XW[(size_t)(m0 + row) * FEAT + n0 + r] = f2bf(acc[reg]);
  }
}

// ---------------- aggregation: wave/node, 8-edge ILP, bf16 messages ------
// msg: bf16 [N][128]; lane covers features {2*lane, 2*lane+1} (one dword).
// mode 0: h = relu(agg + b) -> bf16 Hout;  mode 1: atomicAdd into f_sum.
__global__ __launch_bounds__(256) void agg_kernel(const ushort* __restrict__ msg,
                                                  const float* __restrict__ dinv,
                                                  const int* __restrict__ ptr,
                                                  const int* __restrict__ cnt,
                                                  const int2* __restrict__ edges,
                                                  const float* __restrict__ bias,
                                                  ushort* __restrict__ Hout,
                                                  float* __restrict__ f_sum,
                                                  const int* __restrict__ batch,
                                                  int mode) {
  int wave = (blockIdx.x * 256 + threadIdx.x) >> 6;
  int lane = threadIdx.x & 63;
  if (wave >= N_NODES) return;
  int v = wave;
  float di = dinv[v];
  const uint32_t* m32 = (const uint32_t*)msg;   // 64 dwords per node row
  uint32_t su = m32[(size_t)v * 64 + lane];
  float sn = di * di;
  float ax0 = bfLo(su) * sn, ay0 = bfHi(su) * sn;
  float ax1 = 0.f, ay1 = 0.f, ax2 = 0.f, ay2 = 0.f, ax3 = 0.f, ay3 = 0.f;
  int start = ptr[v];
  int n = cnt[v];
  int i = 0;
  // peel one edge if start is odd so int4 edge loads are 16B-aligned
  if ((start & 1) && n > 0) {
    int2 e = edges[start];
    uint32_t u = m32[(size_t)e.x * 64 + lane];
    float nrm = __int_as_float(e.y);
    ax0 = fmaf(nrm, bfLo(u), ax0);
    ay0 = fmaf(nrm, bfHi(u), ay0);
    i = 1;
  }
  // main loop: 8 edges per iteration, 8 independent gathers in flight
  for (; i + 8 <= n; i += 8) {
    const int4* ep = (const int4*)(edges + start + i);   // 16B-aligned
    int4 q0 = ep[0], q1 = ep[1], q2 = ep[2], q3 = ep[3];
    uint32_t u0 = m32[(size_t)q0.x * 64 + lane];
    uint32_t u1 = m32[(size_t)q0.z * 64 + lane];
    uint32_t u2 = m32[(size_t)q1.x * 64 + lane];
    uint32_t u3 = m32[(size_t)q1.z * 64 + lane];
    uint32_t u4 = m32[(size_t)q2.x * 64 + lane];
    uint32_t u5 = m32[(size_t)q2.z * 64 + lane];
    uint32_t u6 = m32[(size_t)q3.x * 64 + lane];
    uint32_t u7 = m32[(size_t)q3.z * 64 + lane];
    float n0 = __int_as_float(q0.y), n1 = __int_as_float(q0.w);
    float n2 = __int_as_float(q1.y), n3 = __int_as_float(q1.w);
    float n4 = __int_as_float(q2.y), n5 = __int_as_float(q2.w);
    float n6 = __int_as_float(q3.y), n7 = __int_as_float(q3.w);
    ax0 = fmaf(n0, bfLo(u0), ax0); ay0 = fmaf(n0, bfHi(u0), ay0);
    ax1 = fmaf(n1, bfLo(u1), ax1); ay1 = fmaf(n1, bfHi(u1), ay1);
    ax2 = fmaf(n2, bfLo(u2), ax2); ay2 = fmaf(n2, bfHi(u2), ay2);
    ax3 = fmaf(n3, bfLo(u3), ax3); ay3 = fmaf(n3, bfHi(u3), ay3);
    ax0 = fmaf(n4, bfLo(u4), ax0); ay0 = fmaf(n4, bfHi(u4), ay0);
    ax1 = fmaf(n5, bfLo(u5), ax1); ay1 = fmaf(n5, bfHi(u5), ay1);
    ax2 = fmaf(n6, bfLo(u6), ax2); ay2 = fmaf(n6, bfHi(u6), ay2);
    ax3 = fmaf(n7, bfLo(u7), ax3); ay3 = fmaf(n7, bfHi(u7), ay3);
  }
  // tail
  for (; i < n; ++i) {
    int2 e = edges[start + i];
    float nrm = __int_as_float(e.y);
    uint32_t u = m32[(size_t)e.x * 64 + lane];
    ax0 = fmaf(nrm, bfLo(u), ax0);
    ay0 = fmaf(nrm, bfHi(u), ay0);
  }
  float ax = (ax0 + ax1) + (ax2 + ax3) + bias[2 * lane];
  float ay = (ay0 + ay1) + (ay2 + ay3) + bias[2 * lane + 1];
  if (mode == 0) {
    ax = fmaxf(ax, 0.f);
    ay = fmaxf(ay, 0.f);
    ushort2 h2;
    h2.x = f2bf(ax);
    h2.y = f2bf(ay);
    ((ushort2*)Hout)[(size_t)v * 64 + lane] = h2;
  } else {
    int g = batch[v];
    atomicAdd(&f_sum[g * FEAT + 2 * lane], ax);
    atomicAdd(&f_sum[g * FEAT + 2 * lane + 1], ay);
  }
}

// ---------------- per-graph node counts (LDS binned) ---------------------
__global__ __launch_bounds__(256) void count_graphs(const int* __restrict__ batch,
                                                    float* __restrict__ cnt_g) {
  __shared__ int bins[NGRAPH];
  if (threadIdx.x < NGRAPH) bins[threadIdx.x] = 0;
  __syncthreads();
  int i = blockIdx.x * 256 + threadIdx.x;
  if (i < N_NODES) atomicAdd(&bins[batch[i]], 1);
  __syncthreads();
  if (threadIdx.x < NGRAPH && bins[threadIdx.x] > 0)
    atomicAdd(&cnt_g[threadIdx.x], (float)bins[threadIdx.x]);
}

// ---------------- finalize f = sums / cnt (fp32, output 0) ---------------
__global__ __launch_bounds__(256) void finalize_f(const float* __restrict__ f_sum,
                                                  const float* __restrict__ cnt_g,
                                                  float* __restrict__ out_f) {
  int i = blockIdx.x * 256 + threadIdx.x;
  if (i < NGRAPH * FEAT) {
    float c = fmaxf(cnt_g[i >> 7], 1.0f);
    out_f[i] = f_sum[i] / c;
  }
}

// ---------------- FC head: split-K atomic GEMM ---------------------------
__global__ __launch_bounds__(256) void fc_init(const float* __restrict__ b,
                                               float* __restrict__ out, int C) {
  int i = blockIdx.x * 256 + threadIdx.x;
  if (i < NGRAPH * C) out[i] = b[i % C];
}

__global__ __launch_bounds__(256) void fc_accum(const float* __restrict__ in,
                                                const float* __restrict__ w,
                                                float* __restrict__ out,
                                                int K, int C, int relu_in,
                                                int cstrips, int kchunks) {
  int wave = (blockIdx.x * 256 + threadIdx.x) >> 6;
  int lane = threadIdx.x & 63;
  int perrow = cstrips * kchunks;
  int r = wave / perrow;
  if (r >= NGRAPH) return;
  int rem = wave - r * perrow;
  int cs = rem / kchunks;
  int kc = rem - cs * kchunks;
  int c = cs * 64 + lane;
  if (c >= C) return;
  const float* inr = in + (size_t)r * K + kc * 64;
  const float* wp = w + (size_t)(kc * 64) * C + c;
  float a0 = 0.f, a1 = 0.f, a2 = 0.f, a3 = 0.f;
#pragma unroll 4
  for (int k = 0; k < 64; k += 4) {
    float i0 = inr[k], i1 = inr[k + 1], i2 = inr[k + 2], i3 = inr[k + 3];
    if (relu_in) {
      i0 = fmaxf(i0, 0.f); i1 = fmaxf(i1, 0.f);
      i2 = fmaxf(i2, 0.f); i3 = fmaxf(i3, 0.f);
    }
    a0 = fmaf(i0, wp[(size_t)k * C], a0);
    a1 = fmaf(i1, wp[(size_t)(k + 1) * C], a1);
    a2 = fmaf(i2, wp[(size_t)(k + 2) * C], a2);
    a3 = fmaf(i3, wp[(size_t)(k + 3) * C], a3);
  }
  atomicAdd(&out[(size_t)r * C + c], (a0 + a1) + (a2 + a3));
}

static inline void fc_run(const float* in, const float* w, const float* b,
                          float* out, int K, int C, int relu_in,
                          hipStream_t stream) {
  int cstrips = (C + 63) / 64;
  int kchunks = K / 64;
  fc_init<<<(NGRAPH * C + 255) / 256, 256, 0, stream>>>(b, out, C);
  int waves = NGRAPH * cstrips * kchunks;
  fc_accum<<<(waves * 64 + 255) / 256, 256, 0, stream>>>(in, w, out, K, C,
                                                         relu_in, cstrips, kchunks);
}

// =========================================================================
extern "C" void kernel_launch(void* const* d_in, const int* in_sizes, int n_in,
                              void* d_out, int out_size, void* d_ws, size_t ws_size,
                              hipStream_t stream) {
  const float* x         = (const float*)d_in[0];
  const int*   ei        = (const int*)d_in[1];     // [2][E]: row0 src, row1 dst
  const int*   batch     = (const int*)d_in[2];
  const float* conv_w[3] = {(const float*)d_in[3], (const float*)d_in[5], (const float*)d_in[7]};
  const float* conv_b[3] = {(const float*)d_in[4], (const float*)d_in[6], (const float*)d_in[8]};
  const float* fc_w[5]   = {(const float*)d_in[9],  (const float*)d_in[11],
                            (const float*)d_in[13], (const float*)d_in[15],
                            (const float*)d_in[17]};
  const float* fc_b[5]   = {(const float*)d_in[10], (const float*)d_in[12],
                            (const float*)d_in[14], (const float*)d_in[16],
                            (const float*)d_in[18]};
  const int* e_src = ei;
  const int* e_dst = ei + N_EDGES;
  float* out_f = (float*)d_out;                  // [64][128] fp32  (output 0)
  float* out_y = (float*)d_out + NGRAPH * FEAT;  // [64][10]  fp32  (output 1)

  char* p = (char*)d_ws;
  auto carve = [&](size_t bytes) {
    char* r = p;
    p += (bytes + 255) & ~(size_t)255;
    return r;
  };
  int*    cnt_i   = (int*)carve(N_NODES * 4);
  float*  dinv    = (float*)carve(N_NODES * 4);
  int*    csr_ptr = (int*)carve(N_NODES * 4);
  int*    cursor  = (int*)carve(N_NODES * 4);
  int*    bsums   = (int*)carve(256 * 4);
  int2*   edges   = (int2*)carve((size_t)N_EDGES * 8);
  ushort* xb      = (ushort*)carve((size_t)N_NODES * FEAT * 2);   // bf16 x
  ushort* wb      = (ushort*)carve((size_t)3 * FEAT * FEAT * 2);  // bf16 conv weights
  ushort* msl     = (ushort*)carve((size_t)N_NODES * FEAT * 2);   // bf16 messages XW
  ushort* hbuf    = (ushort*)carve((size_t)N_NODES * FEAT * 2);   // bf16 h
  float*  f_sum   = (float*)carve(NGRAPH * FEAT * 4);
  float*  cnt_g   = (float*)carve(NGRAPH * 4);
  float*  act1    = (float*)carve(NGRAPH * 1024 * 4);
  float*  act2    = (float*)carve(NGRAPH * 512 * 4);
  float*  act3    = (float*)carve(NGRAPH * 256 * 4);
  float*  act4    = (float*)carve(NGRAPH * 128 * 4);

  const int BLK_E = (N_EDGES + 255) / 256;
  const int BLK_N = (N_NODES + 255) / 256;

  hipMemsetAsync(cnt_i, 0, N_NODES * 4, stream);
  hipMemsetAsync(f_sum, 0, NGRAPH * FEAT * 4, stream);
  hipMemsetAsync(cnt_g, 0, NGRAPH * 4, stream);

  // ---- fp32 -> bf16 prep (x, conv weights) ----
  cvt_bf16<<<(N_NODES * FEAT / 4 + 255) / 256, 256, 0, stream>>>(x, xb, N_NODES * FEAT / 4);
  cvt_bf16<<<(FEAT * FEAT / 4 + 255) / 256, 256, 0, stream>>>(conv_w[0], wb,                   FEAT * FEAT / 4);
  cvt_bf16<<<(FEAT * FEAT / 4 + 255) / 256, 256, 0, stream>>>(conv_w[1], wb + FEAT * FEAT,     FEAT * FEAT / 4);
  cvt_bf16<<<(FEAT * FEAT / 4 + 255) / 256, 256, 0, stream>>>(conv_w[2], wb + 2 * FEAT * FEAT, FEAT * FEAT / 4);

  // ---- build CSR + norms (reused by all 3 convs) ----
  count_deg<<<BLK_E, 256, 0, stream>>>(e_dst, cnt_i);
  compute_dinv<<<BLK_N, 256, 0, stream>>>(cnt_i, dinv);
  scan1<<<BLK_N, 256, 0, stream>>>(cnt_i, csr_ptr, bsums);
  scan2<<<1, 256, 0, stream>>>(bsums, BLK_N);
  scan3<<<BLK_N, 256, 0, stream>>>(csr_ptr, cursor, bsums);
  fill_csr<<<BLK_E, 256, 0, stream>>>(e_src, e_dst, dinv, cursor, edges);

  const int GEMM_BLKS = (N_NODES / 16) * 8 / 4;
  const int AGG_BLKS  = (N_NODES + 3) / 4;

  // ---- conv1 ----
  gemm128<<<GEMM_BLKS, 256, 0, stream>>>(xb, wb, msl, N_NODES / 16);
  agg_kernel<<<AGG_BLKS, 256, 0, stream>>>(msl, dinv, csr_ptr, cnt_i, edges,
                                           conv_b[0], hbuf, f_sum, batch, 0);
  // ---- conv2 ----
  gemm128<<<GEMM_BLKS, 256, 0, stream>>>(hbuf, wb + FEAT * FEAT, msl, N_NODES / 16);
  agg_kernel<<<AGG_BLKS, 256, 0, stream>>>(msl, dinv, csr_ptr, cnt_i, edges,
                                           conv_b[1], hbuf, f_sum, batch, 0);
  // ---- conv3 + fused mean-pool numerator ----
  gemm128<<<GEMM_BLKS, 256, 0, stream>>>(hbuf, wb + 2 * FEAT * FEAT, msl, N_NODES / 16);
  agg_kernel<<<AGG_BLKS, 256, 0, stream>>>(msl, dinv, csr_ptr, cnt_i, edges,
                                           conv_b[2], hbuf, f_sum, batch, 1);

  // ---- pool ----
  count_graphs<<<BLK_N, 256, 0, stream>>>(batch, cnt_g);
  finalize_f<<<(NGRAPH * FEAT + 255) / 256, 256, 0, stream>>>(f_sum, cnt_g, out_f);

  // ---- FC head: split-K atomic GEMMs, relu fused into next layer's read ----
  fc_run(out_f, fc_w[0], fc_b[0], act1, 128, 1024, 0, stream);
  fc_run(act1,  fc_w[1], fc_b[1], act2, 1024, 512, 1, stream);
  fc_run(act2,  fc_w[2], fc_b[2], act3, 512, 256, 1, stream);
  fc_run(act3,  fc_w[3], fc_b[3], act4, 256, 128, 1, stream);
  fc_run(act4,  fc_w[4], fc_b[4], out_y, 128, 10, 1, stream);
}